// Round 1
// baseline (346.094 us; speedup 1.0000x reference)
//
#include <hip/hip_runtime.h>

// Problem constants (from setup_inputs: B=8, Hs=Ws=256, H=W=512, niter=5)
#define B_    8
#define HS_   256
#define WS_   256
#define H_    512
#define W_    512
#define HW_   (H_ * W_)          // 262144
#define NITER 5
#define PPAD  (NITER + 1)        // 6
#define P_    (W_ + 2 * PPAD)    // 524
#define PP_   (P_ * P_)          // 274576

// ---------------------------------------------------------------------------
// Bilinear upsample of (src - base) from 256x256 -> 512x512, channels x,y.
// Mirrors numpy/XLA op order exactly; fp contraction OFF so the fp32 results
// bitwise-match the reference, which matters because rint() / OOB decisions
// feed the scatter mask.
// ---------------------------------------------------------------------------
__device__ __forceinline__ void bilin_disp(const float* __restrict__ src,
                                           const float* __restrict__ base,
                                           int b, int y, int x,
                                           float& dx, float& dy) {
#pragma clang fp contract(off)
    // coords: c = (i+0.5)*0.5 - 0.5, clip [0, 255]  (exact fp32 arithmetic)
    float cy = ((float)y + 0.5f) * 0.5f - 0.5f;
    cy = fminf(fmaxf(cy, 0.0f), 255.0f);
    int   y0 = (int)floorf(cy);
    int   y1 = min(y0 + 1, HS_ - 1);
    float wy = cy - (float)y0;

    float cx = ((float)x + 0.5f) * 0.5f - 0.5f;
    cx = fminf(fmaxf(cx, 0.0f), 255.0f);
    int   x0 = (int)floorf(cx);
    int   x1 = min(x0 + 1, WS_ - 1);
    float wx = cx - (float)x0;

    float omy = 1.0f - wy;
    float omx = 1.0f - wx;

    int i00 = ((b * HS_ + y0) * WS_ + x0) * 2;
    int i10 = ((b * HS_ + y1) * WS_ + x0) * 2;
    int i01 = ((b * HS_ + y0) * WS_ + x1) * 2;
    int i11 = ((b * HS_ + y1) * WS_ + x1) * 2;
    int b00 = (y0 * WS_ + x0) * 2;
    int b10 = (y1 * WS_ + x0) * 2;
    int b01 = (y0 * WS_ + x1) * 2;
    int b11 = (y1 * WS_ + x1) * 2;

    // channel 0 -> dx
    {
        float a00 = src[i00 + 0] - base[b00 + 0];
        float a10 = src[i10 + 0] - base[b10 + 0];
        float a01 = src[i01 + 0] - base[b01 + 0];
        float a11 = src[i11 + 0] - base[b11 + 0];
        float r0 = a00 * omy + a10 * wy;   // blend along y first (matches ref)
        float r1 = a01 * omy + a11 * wy;
        float v  = r0 * omx + r1 * wx;     // then along x
        dx = v * 256.0f;                   // * (W/2), exact pow2 scale
    }
    // channel 1 -> dy
    {
        float a00 = src[i00 + 1] - base[b00 + 1];
        float a10 = src[i10 + 1] - base[b10 + 1];
        float a01 = src[i01 + 1] - base[b01 + 1];
        float a11 = src[i11 + 1] - base[b11 + 1];
        float r0 = a00 * omy + a10 * wy;
        float r1 = a01 * omy + a11 * wy;
        float v  = r0 * omx + r1 * wx;
        dy = v * 256.0f;                   // * (H/2)
    }
}

// Pass 1: each source pixel j computes its rounded target cell; smallest j
// wins each cell (reference: stable argsort + keep-first + scatter).
__global__ void scatter_k(const float* __restrict__ src,
                          const float* __restrict__ base,
                          int* __restrict__ winner) {
    int i = blockIdx.x * blockDim.x + threadIdx.x;
    if (i >= B_ * HW_) return;
    int b = i / HW_;
    int j = i - b * HW_;
    int y = j / W_;
    int x = j - y * W_;
    float dx, dy;
    bilin_disp(src, base, b, y, x, dx, dy);
    int xi = (int)rintf((float)x + dx);    // rint == round-half-even == jnp.round
    int yi = (int)rintf((float)y + dy);
    if (xi >= 0 && yi >= 0 && xi < W_ && yi < H_) {
        atomicMin(&winner[b * HW_ + yi * W_ + xi], j);
    }
}

// Pass 2: winner writes -dx,-dy and mask=1 into the padded (524x524) arrays.
__global__ void fill_k(const float* __restrict__ src,
                       const float* __restrict__ base,
                       const int* __restrict__ winner,
                       float* __restrict__ idxA,
                       float* __restrict__ idyA,
                       unsigned char* __restrict__ maskA) {
    int i = blockIdx.x * blockDim.x + threadIdx.x;
    if (i >= B_ * HW_) return;
    int b = i / HW_;
    int j = i - b * HW_;
    int y = j / W_;
    int x = j - y * W_;
    float dx, dy;
    bilin_disp(src, base, b, y, x, dx, dy);
    int xi = (int)rintf((float)x + dx);
    int yi = (int)rintf((float)y + dy);
    if (xi >= 0 && yi >= 0 && xi < W_ && yi < H_) {
        int t = b * HW_ + yi * W_ + xi;
        if (winner[t] == j) {
            int pidx = b * PP_ + (yi + PPAD) * P_ + (xi + PPAD);
            idxA[pidx]  = -dx;
            idyA[pidx]  = -dy;
            maskA[pidx] = 1;
        }
    }
}

// One diffusion iteration: newly-reachable cells (4-neighbor dilation of
// mask) get the kernel-weighted average of masked 3x3 neighbors.
// Unmasked inv values are always 0, so conv(inv) == sum over masked nbrs.
__global__ void diffuse_k(const float* __restrict__ sdx,
                          const float* __restrict__ sdy,
                          const unsigned char* __restrict__ sm,
                          float* __restrict__ ddx,
                          float* __restrict__ ddy,
                          unsigned char* __restrict__ dm,
                          const float* __restrict__ kern) {
    int i = blockIdx.x * blockDim.x + threadIdx.x;
    if (i >= B_ * PP_) return;
    int b    = i / PP_;
    int cell = i - b * PP_;
    int y    = cell / P_;
    int x    = cell - y * P_;

    unsigned char m = sm[i];
    if (m) {  // already masked: keep value
        dm[i]  = 1;
        ddx[i] = sdx[i];
        ddy[i] = sdy[i];
        return;
    }
    bool up = (y > 0)      && sm[i - P_];
    bool dn = (y < P_ - 1) && sm[i + P_];
    bool lf = (x > 0)      && sm[i - 1];
    bool rt = (x < P_ - 1) && sm[i + 1];
    if (!(up | dn | lf | rt)) {  // not reachable this iteration
        dm[i]  = 0;
        ddx[i] = sdx[i];
        ddy[i] = sdy[i];
        return;
    }
    float s = 0.0f, vx = 0.0f, vy = 0.0f;
    for (int ky = 0; ky < 3; ky++) {
        int yy = y + ky - 1;
        if (yy < 0 || yy >= P_) continue;
        for (int kx = 0; kx < 3; kx++) {
            int xx = x + kx - 1;
            if (xx < 0 || xx >= P_) continue;
            int n = b * PP_ + yy * P_ + xx;
            if (sm[n]) {
                float kw = kern[ky * 3 + kx];
                s  += kw;
                vx += kw * sdx[n];
                vy += kw * sdy[n];
            }
        }
    }
    dm[i]  = 1;
    ddx[i] = vx / s;
    ddy[i] = vy / s;
}

// One erosion iteration: keep mask only if all 4 neighbors masked
// (out-of-array counts as True, matching pad(..., constant_values=True)).
__global__ void erode_k(const unsigned char* __restrict__ sm,
                        unsigned char* __restrict__ dm) {
    int i = blockIdx.x * blockDim.x + threadIdx.x;
    if (i >= B_ * PP_) return;
    int b    = i / PP_;
    int cell = i - b * PP_;
    int y    = cell / P_;
    int x    = cell - y * P_;
    unsigned char m = sm[i];
    if (m) {
        bool up = (y == 0)      || sm[i - P_];
        bool dn = (y == P_ - 1) || sm[i + P_];
        bool lf = (x == 0)      || sm[i - 1];
        bool rt = (x == P_ - 1) || sm[i + 1];
        m = (up && dn && lf && rt) ? 1 : 0;
    }
    dm[i] = m;
}

// Final compose: out = tgt + where(mask, inv * (1/256), 4.0)
__global__ void final_k(const unsigned char* __restrict__ m,
                        const float* __restrict__ idx,
                        const float* __restrict__ idy,
                        const float* __restrict__ tgt,
                        float* __restrict__ out) {
    int i = blockIdx.x * blockDim.x + threadIdx.x;
    if (i >= B_ * HW_) return;
    int b    = i / HW_;
    int cell = i - b * HW_;
    int y    = cell / W_;
    int x    = cell - y * W_;
    int pidx = b * PP_ + (y + PPAD) * P_ + (x + PPAD);
    bool mm = m[pidx] != 0;
    float vx = mm ? idx[pidx] * (1.0f / 256.0f) : 4.0f;  // 2/W exact
    float vy = mm ? idy[pidx] * (1.0f / 256.0f) : 4.0f;  // 2/H exact
    int t = cell * 2;
    out[(size_t)i * 2 + 0] = tgt[t + 0] + vx;
    out[(size_t)i * 2 + 1] = tgt[t + 1] + vy;
}

extern "C" void kernel_launch(void* const* d_in, const int* in_sizes, int n_in,
                              void* d_out, int out_size, void* d_ws, size_t ws_size,
                              hipStream_t stream) {
    const float* src  = (const float*)d_in[0];  // (8,256,256,2)
    const float* kern = (const float*)d_in[1];  // (3,3)
    const float* base = (const float*)d_in[2];  // (1,256,256,2)
    const float* tgt  = (const float*)d_in[3];  // (1,512,512,2)
    // d_in[4] = niter (5) — fixed for this problem, hardcoded as NITER.
    float* out = (float*)d_out;                 // (8,512,512,2)

    char*  ws = (char*)d_ws;
    size_t o  = 0;
    auto alloc = [&](size_t bytes) {
        void* p = ws + o;
        o += (bytes + 255) & ~(size_t)255;
        return p;
    };
    int*           winner = (int*)alloc((size_t)B_ * HW_ * sizeof(int));
    float*         dxA    = (float*)alloc((size_t)B_ * PP_ * sizeof(float));
    float*         dxB    = (float*)alloc((size_t)B_ * PP_ * sizeof(float));
    float*         dyA    = (float*)alloc((size_t)B_ * PP_ * sizeof(float));
    float*         dyB    = (float*)alloc((size_t)B_ * PP_ * sizeof(float));
    unsigned char* mA     = (unsigned char*)alloc((size_t)B_ * PP_);
    unsigned char* mB     = (unsigned char*)alloc((size_t)B_ * PP_);

    // winner = 0x7F7F7F7F (> any source index); padded value/mask arrays = 0
    hipMemsetAsync(winner, 0x7F, (size_t)B_ * HW_ * sizeof(int), stream);
    hipMemsetAsync(dxA, 0, (size_t)B_ * PP_ * sizeof(float), stream);
    hipMemsetAsync(dyA, 0, (size_t)B_ * PP_ * sizeof(float), stream);
    hipMemsetAsync(mA, 0, (size_t)B_ * PP_, stream);

    int nsrc = B_ * HW_;
    int gsrc = (nsrc + 255) / 256;
    scatter_k<<<gsrc, 256, 0, stream>>>(src, base, winner);
    fill_k<<<gsrc, 256, 0, stream>>>(src, base, winner, dxA, dyA, mA);

    int ncell = B_ * PP_;
    int gcell = (ncell + 255) / 256;

    float *sdx = dxA, *sdy = dyA, *ddx = dxB, *ddy = dyB;
    unsigned char *smm = mA, *dmm = mB;
    for (int it = 0; it < NITER; it++) {
        diffuse_k<<<gcell, 256, 0, stream>>>(sdx, sdy, smm, ddx, ddy, dmm, kern);
        float* tf;
        tf = sdx; sdx = ddx; ddx = tf;
        tf = sdy; sdy = ddy; ddy = tf;
        unsigned char* tm = smm; smm = dmm; dmm = tm;
    }
    // current state: values in (sdx, sdy), mask in smm
    unsigned char *cm = smm, *om = dmm;
    for (int it = 0; it < NITER; it++) {
        erode_k<<<gcell, 256, 0, stream>>>(cm, om);
        unsigned char* tm = cm; cm = om; om = tm;
    }

    final_k<<<gsrc, 256, 0, stream>>>(cm, sdx, sdy, tgt, out);
}

// Round 2
// 235.589 us; speedup vs baseline: 1.4691x; 1.4691x over previous
//
#include <hip/hip_runtime.h>

// Problem constants (from setup_inputs: B=8, Hs=Ws=256, H=W=512, niter=5)
#define B_    8
#define HS_   256
#define WS_   256
#define H_    512
#define W_    512
#define HW_   (H_ * W_)          // 262144
#define NITER 5
#define PPAD  (NITER + 1)        // 6
#define P_    (W_ + 2 * PPAD)    // 524
#define PP_   (P_ * P_)          // 274576
#define INF_  0x7F7F7F7F
#define LS    42                 // 32 output + 2*5 halo

// ---------------------------------------------------------------------------
// Bilinear upsample of (src - base) from 256x256 -> 512x512, channels x,y.
// Mirrors numpy op order exactly; fp contraction OFF so fp32 results
// bitwise-match the reference (rint/OOB decisions depend on these bits).
// ---------------------------------------------------------------------------
__device__ __forceinline__ void bilin_disp(const float* __restrict__ src,
                                           const float* __restrict__ base,
                                           int b, int y, int x,
                                           float& dx, float& dy) {
#pragma clang fp contract(off)
    float cy = ((float)y + 0.5f) * 0.5f - 0.5f;
    cy = fminf(fmaxf(cy, 0.0f), 255.0f);
    int   y0 = (int)floorf(cy);
    int   y1 = min(y0 + 1, HS_ - 1);
    float wy = cy - (float)y0;

    float cx = ((float)x + 0.5f) * 0.5f - 0.5f;
    cx = fminf(fmaxf(cx, 0.0f), 255.0f);
    int   x0 = (int)floorf(cx);
    int   x1 = min(x0 + 1, WS_ - 1);
    float wx = cx - (float)x0;

    float omy = 1.0f - wy;
    float omx = 1.0f - wx;

    int i00 = ((b * HS_ + y0) * WS_ + x0) * 2;
    int i10 = ((b * HS_ + y1) * WS_ + x0) * 2;
    int i01 = ((b * HS_ + y0) * WS_ + x1) * 2;
    int i11 = ((b * HS_ + y1) * WS_ + x1) * 2;
    int b00 = (y0 * WS_ + x0) * 2;
    int b10 = (y1 * WS_ + x0) * 2;
    int b01 = (y0 * WS_ + x1) * 2;
    int b11 = (y1 * WS_ + x1) * 2;

    {
        float a00 = src[i00 + 0] - base[b00 + 0];
        float a10 = src[i10 + 0] - base[b10 + 0];
        float a01 = src[i01 + 0] - base[b01 + 0];
        float a11 = src[i11 + 0] - base[b11 + 0];
        float r0 = a00 * omy + a10 * wy;
        float r1 = a01 * omy + a11 * wy;
        float v  = r0 * omx + r1 * wx;
        dx = v * 256.0f;
    }
    {
        float a00 = src[i00 + 1] - base[b00 + 1];
        float a10 = src[i10 + 1] - base[b10 + 1];
        float a01 = src[i01 + 1] - base[b01 + 1];
        float a11 = src[i11 + 1] - base[b11 + 1];
        float r0 = a00 * omy + a10 * wy;
        float r1 = a01 * omy + a11 * wy;
        float v  = r0 * omx + r1 * wx;
        dy = v * 256.0f;
    }
}

// Pass 1: atomicMin scatter, XCD-banded.
// Block n -> XCD n%8 (round-robin heuristic); XCD k handles source rows
// [k*64, (k+1)*64) of every batch, so its atomics target a ~2.7 MB winner
// footprint (band +/- max displacement) that fits its private 4 MB L2 —
// kills the dirty-line replication/writeback churn seen in R0 (56 MB).
__global__ void scatter_k(const float* __restrict__ src,
                          const float* __restrict__ base,
                          int* __restrict__ winner) {
    int n   = blockIdx.x;        // 8192 blocks of 256 = exactly B*H*W sources
    int xcd = n & 7;
    int m   = n >> 3;            // 0..1023
    int b   = m >> 7;            // 0..7
    int r   = m & 127;           // 0..127: 128 blocks cover 64 rows (half-row each)
    int y   = xcd * 64 + (r >> 1);
    int x   = ((r & 1) << 8) + threadIdx.x;

    float dx, dy;
    bilin_disp(src, base, b, y, x, dx, dy);
    int xi = (int)rintf((float)x + dx);    // rint == round-half-even == jnp.round
    int yi = (int)rintf((float)y + dy);
    if (xi >= 0 && yi >= 0 && xi < W_ && yi < H_) {
        int j = y * W_ + x;
        atomicMin(&winner[b * HW_ + yi * W_ + xi], j);
    }
}

// Pass 2 (gather): one thread per padded cell. Reads winner coalesced,
// recomputes the winner's displacement (deterministic, bit-identical to
// scatter), writes dx/dy/mask fully coalesced. Also zero-fills pad ring,
// so no memsets of the padded arrays are needed.
__global__ void fill_k(const float* __restrict__ src,
                       const float* __restrict__ base,
                       const int* __restrict__ winner,
                       float* __restrict__ dxA,
                       float* __restrict__ dyA,
                       unsigned char* __restrict__ mA) {
    int i = blockIdx.x * blockDim.x + threadIdx.x;
    if (i >= B_ * PP_) return;
    int b    = i / PP_;
    int cell = i - b * PP_;
    int py   = cell / P_;
    int px   = cell - py * P_;
    float vx = 0.0f, vy = 0.0f;
    unsigned char mm = 0;
    int iy = py - PPAD, ix = px - PPAD;
    if (iy >= 0 && iy < H_ && ix >= 0 && ix < W_) {
        int w = winner[b * HW_ + iy * W_ + ix];
        if (w != INF_) {
            int sy = w >> 9, sx = w & (W_ - 1);
            float dx, dy;
            bilin_disp(src, base, b, sy, sx, dx, dy);
            vx = -dx; vy = -dy; mm = 1;
        }
    }
    dxA[i] = vx; dyA[i] = vy; mA[i] = mm;
}

// Fused 5-iteration mask-dilating gaussian diffusion, LDS-tiled.
// 32x32 output per block, halo 5 (42x42 load), double-buffered.
// All iterations compute the constant region [1,41): the unwritten ring 0
// goes stale after iter 0, and staleness propagates 1 ring/iter — after 5
// iters rings 0..4 are wrong, rings >=5 (the stored 32x32 interior) exact.
__launch_bounds__(256)
__global__ void diffuse5_k(const float* __restrict__ sdx,
                           const float* __restrict__ sdy,
                           const unsigned char* __restrict__ sm,
                           float* __restrict__ ddx,
                           float* __restrict__ ddy,
                           unsigned char* __restrict__ dm,
                           const float* __restrict__ kern) {
    __shared__ float bdx[2][LS][LS + 1];
    __shared__ float bdy[2][LS][LS + 1];
    __shared__ unsigned char bm[2][LS][LS + 2];

    int b  = blockIdx.z;
    int oy = blockIdx.y * 32;   // tile origin in padded coords
    int ox = blockIdx.x * 32;
    int tid = threadIdx.x;

    float kw[9];
#pragma unroll
    for (int q = 0; q < 9; q++) kw[q] = kern[q];

    int bof = b * PP_;
    for (int idx = tid; idx < LS * LS; idx += 256) {
        int i = idx / LS, j = idx - (idx / LS) * LS;
        int py = oy + i - 5, px = ox + j - 5;
        float vx = 0.0f, vy = 0.0f;
        unsigned char mm = 0;
        if (py >= 0 && py < P_ && px >= 0 && px < P_) {
            int g = bof + py * P_ + px;
            vx = sdx[g]; vy = sdy[g]; mm = sm[g];
        }
        bdx[0][i][j] = vx; bdy[0][i][j] = vy; bm[0][i][j] = mm;
    }
    __syncthreads();

    int s = 0;
    for (int it = 0; it < 5; it++) {
        int d = s ^ 1;
        for (int idx = tid; idx < 40 * 40; idx += 256) {
            int i = 1 + idx / 40, j = 1 + idx - (idx / 40) * 40;
            unsigned char mm = bm[s][i][j];
            float vx, vy; unsigned char om;
            if (mm) {
                vx = bdx[s][i][j]; vy = bdy[s][i][j]; om = 1;
            } else {
                int nb = bm[s][i - 1][j] | bm[s][i + 1][j] |
                         bm[s][i][j - 1] | bm[s][i][j + 1];
                if (nb) {
                    float ssum = 0.0f, ax = 0.0f, ay = 0.0f;
#pragma unroll
                    for (int ky = 0; ky < 3; ky++) {
#pragma unroll
                        for (int kx = 0; kx < 3; kx++) {
                            if (bm[s][i + ky - 1][j + kx - 1]) {
                                float w = kw[ky * 3 + kx];
                                ssum += w;
                                ax += w * bdx[s][i + ky - 1][j + kx - 1];
                                ay += w * bdy[s][i + ky - 1][j + kx - 1];
                            }
                        }
                    }
                    vx = ax / ssum; vy = ay / ssum; om = 1;
                } else {
                    vx = 0.0f; vy = 0.0f; om = 0;
                }
            }
            bdx[d][i][j] = vx; bdy[d][i][j] = vy; bm[d][i][j] = om;
        }
        __syncthreads();
        s = d;
    }

    for (int idx = tid; idx < 32 * 32; idx += 256) {
        int i = 5 + (idx >> 5), j = 5 + (idx & 31);
        int py = oy + i - 5, px = ox + j - 5;
        if (py < P_ && px < P_) {
            int g = bof + py * P_ + px;
            ddx[g] = bdx[s][i][j];
            ddy[g] = bdy[s][i][j];
            dm[g]  = bm[s][i][j];
        }
    }
}

// Fused 5-iteration 4-neighbor erosion + final compose, LDS-tiled.
// Output interior cells never need the True-boundary rule (pad=6 > halo=5,
// and the dilated mask can't reach the outermost pad ring), and the halo
// window [oy+1, oy+42] always lies inside the padded array.
__launch_bounds__(256)
__global__ void erodefinal_k(const unsigned char* __restrict__ sm,
                             const float* __restrict__ sdx,
                             const float* __restrict__ sdy,
                             const float* __restrict__ tgt,
                             float* __restrict__ out) {
    __shared__ unsigned char bm[2][LS][LS + 2];
    int b  = blockIdx.z;
    int oy = blockIdx.y * 32;   // tile origin in OUTPUT coords
    int ox = blockIdx.x * 32;
    int tid = threadIdx.x;
    int bof = b * PP_;

    // LDS (i,j) <-> padded (oy+1+i, ox+1+j)  (output (y,x) <-> padded (y+6,x+6))
    for (int idx = tid; idx < LS * LS; idx += 256) {
        int i = idx / LS, j = idx - (idx / LS) * LS;
        bm[0][i][j] = sm[bof + (oy + 1 + i) * P_ + (ox + 1 + j)];
    }
    __syncthreads();

    int s = 0;
    for (int it = 0; it < 5; it++) {
        int d = s ^ 1;
        for (int idx = tid; idx < 40 * 40; idx += 256) {
            int i = 1 + idx / 40, j = 1 + idx - (idx / 40) * 40;
            unsigned char mm = bm[s][i][j];
            if (mm)
                mm = bm[s][i - 1][j] & bm[s][i + 1][j] &
                     bm[s][i][j - 1] & bm[s][i][j + 1];
            bm[d][i][j] = mm;
        }
        __syncthreads();
        s = d;
    }

    for (int idx = tid; idx < 32 * 32; idx += 256) {
        int i = 5 + (idx >> 5), j = 5 + (idx & 31);
        int yy = oy + i - 5, xx = ox + j - 5;       // output coords
        int pidx = bof + (yy + 6) * P_ + (xx + 6);
        bool mm = bm[s][i][j] != 0;
        float vx = mm ? sdx[pidx] * (1.0f / 256.0f) : 4.0f;  // 2/W exact
        float vy = mm ? sdy[pidx] * (1.0f / 256.0f) : 4.0f;  // 2/H exact
        int t = (yy * W_ + xx) * 2;
        size_t o = ((size_t)b * HW_ + yy * W_ + xx) * 2;
        out[o]     = tgt[t]     + vx;
        out[o + 1] = tgt[t + 1] + vy;
    }
}

extern "C" void kernel_launch(void* const* d_in, const int* in_sizes, int n_in,
                              void* d_out, int out_size, void* d_ws, size_t ws_size,
                              hipStream_t stream) {
    const float* src  = (const float*)d_in[0];  // (8,256,256,2)
    const float* kern = (const float*)d_in[1];  // (3,3)
    const float* base = (const float*)d_in[2];  // (1,256,256,2)
    const float* tgt  = (const float*)d_in[3];  // (1,512,512,2)
    float* out = (float*)d_out;                 // (8,512,512,2)

    char*  ws = (char*)d_ws;
    size_t o  = 0;
    auto alloc = [&](size_t bytes) {
        void* p = ws + o;
        o += (bytes + 255) & ~(size_t)255;
        return p;
    };
    int*           winner = (int*)alloc((size_t)B_ * HW_ * sizeof(int));
    float*         dxA    = (float*)alloc((size_t)B_ * PP_ * sizeof(float));
    float*         dxB    = (float*)alloc((size_t)B_ * PP_ * sizeof(float));
    float*         dyA    = (float*)alloc((size_t)B_ * PP_ * sizeof(float));
    float*         dyB    = (float*)alloc((size_t)B_ * PP_ * sizeof(float));
    unsigned char* mA     = (unsigned char*)alloc((size_t)B_ * PP_);
    unsigned char* mB     = (unsigned char*)alloc((size_t)B_ * PP_);

    hipMemsetAsync(winner, 0x7F, (size_t)B_ * HW_ * sizeof(int), stream);

    scatter_k<<<8192, 256, 0, stream>>>(src, base, winner);

    int gfill = (B_ * PP_ + 255) / 256;
    fill_k<<<gfill, 256, 0, stream>>>(src, base, winner, dxA, dyA, mA);

    diffuse5_k<<<dim3(17, 17, B_), 256, 0, stream>>>(dxA, dyA, mA,
                                                     dxB, dyB, mB, kern);

    erodefinal_k<<<dim3(16, 16, B_), 256, 0, stream>>>(mB, dxB, dyB, tgt, out);
}